// Round 10
// baseline (5718.430 us; speedup 1.0000x reference)
//
#include <hip/hip_runtime.h>
#include <math.h>

// Problem constants
#define S      610
#define E      126
#define BATCH  32
#define T      2048
#define NREG   5000

#define SPAD   640            // padded state dim
#define NT     40             // N-tiles of 16 columns
#define NCH    5              // K-chunks of 128 (5*128 = 640)
#define MBX    16             // batches per block == full MFMA M
#define NBLK   2              // blocks (one per 16-batch group)
#define THREADS 512           // 8 waves = exactly 2 per EU
#define NWAVE  8
#define TPW    5              // tiles per wave: idx*8+wv (idx 0..3 reg) + 32+wv (stream)
#define RT     4              // tiles held in registers
#define AROW   688            // alphaq row stride bytes (16B aligned, 688/16=43 odd)

typedef float f32x4 __attribute__((ext_vector_type(4)));
typedef int   i32x8 __attribute__((ext_vector_type(8)));

union Frag { uint4 q[2]; i32x8 v; };

#define MFMA_SCALED(af, bf, acc) \
    __builtin_amdgcn_mfma_scale_f32_16x16x128_f8f6f4((af), (bf), (acc), 0, 0, \
                                                     0, 0x7F7F7F7F, 0, 0x7F7F7F7F)

// DPP row-rotate add (rows of 16 lanes) — reduction on the VALU pipe.
template <int CTRL>
__device__ __forceinline__ float rotf(float v) {
    int r = __builtin_amdgcn_update_dpp(0, __builtin_bit_cast(int, v),
                                        CTRL, 0xF, 0xF, true);
    return __builtin_bit_cast(float, r);
}
__device__ __forceinline__ float row16_sum(float v) {
    v += rotf<0x128>(v);   // row_ror:8
    v += rotf<0x124>(v);   // row_ror:4
    v += rotf<0x122>(v);   // row_ror:2
    v += rotf<0x121>(v);   // row_ror:1
    return v;
}

// ---------- fp8 e4m3 encode (HW on gfx950, sw fallback) ---------------------
__device__ __forceinline__ unsigned sw_e4m3_enc(float f) {
    if (!(f > 0.f)) return 0u;
    int e; float fr = frexpf(f, &e);
    if (e - 1 < -6) {
        int q = (int)rintf(f * 512.f);
        if (q > 7) q = 7;
        return (unsigned)q;
    }
    int m = (int)rintf(fr * 16.f) - 8;
    int EE = e - 1;
    if (m == 8) { m = 0; EE += 1; }
    if (EE > 8) { EE = 8; m = 7; }
    return (unsigned)(((EE + 7) << 3) | m);
}
__device__ __forceinline__ unsigned pack_quad(float v0, float v1, float v2, float v3) {
#if __has_builtin(__builtin_amdgcn_cvt_pk_fp8_f32)
    int w = 0;
    w = __builtin_amdgcn_cvt_pk_fp8_f32(v0, v1, w, false);
    w = __builtin_amdgcn_cvt_pk_fp8_f32(v2, v3, w, true);
    return (unsigned)w;
#else
    return sw_e4m3_enc(v0) | (sw_e4m3_enc(v1) << 8) |
           (sw_e4m3_enc(v2) << 16) | (sw_e4m3_enc(v3) << 24);
#endif
}
__device__ __forceinline__ unsigned char fp8byte(float v) {
#if __has_builtin(__builtin_amdgcn_cvt_pk_fp8_f32)
    int w = __builtin_amdgcn_cvt_pk_fp8_f32(v, v, 0, false);
    return (unsigned char)(w & 0xFF);
#else
    return (unsigned char)sw_e4m3_enc(v);
#endif
}

// ---------- prep kernels ----------------------------------------------------
__global__ void k_init(unsigned* __restrict__ maxbuf) { maxbuf[0] = 0u; }

__global__ void k_max(const float* __restrict__ A, unsigned* __restrict__ maxbuf) {
    int tid = blockIdx.x * blockDim.x + threadIdx.x;
    float m = 0.f;
    for (int i = tid; i < S * S; i += gridDim.x * blockDim.x) m = fmaxf(m, A[i]);
#pragma unroll
    for (int off = 1; off < 64; off <<= 1) m = fmaxf(m, __shfl_xor(m, off, 64));
    if ((threadIdx.x & 63) == 0) atomicMax(maxbuf, __float_as_uint(m));
}

__global__ void k_scalefin(const unsigned* __restrict__ maxbuf,
                           float* __restrict__ s_out, double* __restrict__ logs_out) {
    float mx = __uint_as_float(maxbuf[0]);
    float s = 224.f / mx;
    s_out[0] = s;
    logs_out[0] = log((double)s);
}

// Pack A*s into fp8 for the scaled-MFMA B operand, K=128 fragments.
__global__ void k_pack8mx(const float* __restrict__ A, const float* __restrict__ s_in,
                          uint4* __restrict__ A8c) {
    int n = blockIdx.x;      // 0..NT-1
    int c = blockIdx.y;      // 0..NCH-1
    int l = threadIdx.x;     // 0..63
    float s = s_in[0];
    int j = n * 16 + (l & 15);
    int kb = c * 128 + (l >> 4) * 32;
#pragma unroll
    for (int h = 0; h < 2; ++h) {
        unsigned dw[4];
#pragma unroll
        for (int r = 0; r < 4; ++r) {
            float v[4];
#pragma unroll
            for (int p = 0; p < 4; ++p) {
                int k = kb + h * 16 + r * 4 + p;
                v[p] = (k < S && j < S) ? A[k * S + j] * s : 0.f;
            }
            dw[r] = pack_quad(v[0], v[1], v[2], v[3]);
        }
        A8c[((n * NCH + c) * 2 + h) * 64 + l] = make_uint4(dw[0], dw[1], dw[2], dw[3]);
    }
}

__global__ void k_bmt(const float* __restrict__ Bm, float* __restrict__ BmT) {
    int j = threadIdx.x;
    int o = blockIdx.x;
    BmT[o * SPAD + j] = (j < S) ? Bm[j * E + o] : 0.f;
}

// One-hot inputs -> observation symbols, TRANSPOSED: obsT[t*BATCH + b].
__global__ void k_obs(const float* __restrict__ in, int* __restrict__ obsT) {
    int i = blockIdx.x * blockDim.x + threadIdx.x;
    if (i >= BATCH * T) return;
    const float2* p = (const float2*)(in + (size_t)i * E);
    int o = 0;
#pragma unroll
    for (int k = 0; k < E / 2; ++k) {
        float2 v = p[k];
        if (v.x > 0.5f) o = 2 * k;
        if (v.y > 0.5f) o = 2 * k + 1;
    }
    int b = i / T, t = i % T;
    obsT[t * BATCH + b] = o;
}

__global__ void k_reg(const float* __restrict__ A, const int* __restrict__ rf,
                      const int* __restrict__ rt, float* __restrict__ out) {
    __shared__ float wpart[16];
    int tid = threadIdx.x;
    float s = 0.f;
    for (int i = tid; i < NREG; i += 1024)
        s += log1pf(-A[rf[i] * S + rt[i]]);
#pragma unroll
    for (int off = 1; off < 64; off <<= 1) s += __shfl_xor(s, off, 64);
    if ((tid & 63) == 0) wpart[tid >> 6] = s;
    __syncthreads();
    if (tid == 0) {
        float t = 0.f;
        for (int w = 0; w < 16; ++w) t += wpart[w];
        out[0] = t;
    }
}

// ---------- forward recursion: 2 blocks, 16 batches, reg-resident B ---------
// Tiles idx*8+wv (idx 0..3) in registers, tile 32+wv streamed from L2.
// o4/em hoisted BEFORE the MFMA chain (latency hides under MFMAs — R8 order).
// z: DPP row16 reduce -> packed float4 zpart -> tid<16 sum -> zsc (3 barriers).
__global__ __launch_bounds__(THREADS, 2) void k_forward(
    const uint4* __restrict__ A8c,
    const float* __restrict__ BmT,
    const int*   __restrict__ obsT,   // [T][BATCH]
    const float* __restrict__ Iv,
    const double* __restrict__ logs,
    double* __restrict__ ll_out)
{
    __shared__ __align__(16) unsigned char alphaq[MBX * AROW];  // 11008 B
    __shared__ __align__(16) f32x4 zpart4[NWAVE][4];            // [wave][quad]
    __shared__ float zsc[MBX];

    const int g    = blockIdx.x;      // group: batches g*16 .. g*16+15
    const int tid  = threadIdx.x;
    const int wv   = tid >> 6;
    const int lane = tid & 63;
    const int mrow = lane & 15;
    const int quad = lane >> 4;
    const int b0   = g * MBX;

    // Preload 4 register tiles (held across the whole t-loop).
    uint4 areg[RT][NCH][2];
#pragma unroll
    for (int rt = 0; rt < RT; ++rt)
#pragma unroll
        for (int c = 0; c < NCH; ++c)
#pragma unroll
            for (int h = 0; h < 2; ++h)
                areg[rt][c][h] = A8c[(((rt * 8 + wv) * NCH + c) * 2 + h) * 64 + lane];

    // ---- t = 0: alpha0 = I*em0 exact, per-batch z, quantize ----------------
    double ll = 0.0;   // thread tid<16 accumulates ll for batch b0+tid
    {
        const int j1 = tid + THREADS;
        const bool hasb = (j1 < SPAD);
        float Ia = (tid < S) ? Iv[tid] : 0.f;
        float Ib = (hasb && j1 < S) ? Iv[j1] : 0.f;
        float v0a[MBX], v0b[MBX], p0[MBX];
#pragma unroll
        for (int m = 0; m < MBX; ++m) {
            int o = obsT[b0 + m];
            v0a[m] = Ia * BmT[o * SPAD + tid];
            v0b[m] = hasb ? Ib * BmT[o * SPAD + j1] : 0.f;
            p0[m] = v0a[m] + v0b[m];
        }
#pragma unroll
        for (int off = 1; off < 64; off <<= 1)
#pragma unroll
            for (int m = 0; m < MBX; ++m) p0[m] += __shfl_xor(p0[m], off, 64);
        if (lane == 0) {
#pragma unroll
            for (int m = 0; m < MBX; ++m) ((float*)zpart4[wv])[m] = p0[m];
        }
        __syncthreads();
        if (tid < MBX) {
            float z = 0.f;
            for (int w = 0; w < NWAVE; ++w) z += ((float*)zpart4[w])[tid];
            ll = (double)logf(z);
            zsc[tid] = 128.f / z;
        }
        __syncthreads();
#pragma unroll
        for (int m = 0; m < MBX; ++m) {
            alphaq[m * AROW + tid] = fp8byte(v0a[m] * zsc[m]);
            if (hasb) alphaq[m * AROW + j1] = fp8byte(v0b[m] * zsc[m]);
        }
        __syncthreads();
    }

    const uint4* sp = A8c + (size_t)((32 + wv) * NCH * 2) * 64 + lane;  // stream tile
    const unsigned char* aqp = alphaq + mrow * AROW + quad * 32;

    // ---- main recursion -----------------------------------------------------
    for (int t = 1; t < T; ++t) {
        // chunk-0 prefetch (global first, then LDS)
        uint4 gs[2][2];
        gs[0][0] = sp[0];
        gs[0][1] = sp[64];
        Frag afc[2];
        afc[0].q[0] = *(const uint4*)(aqp);
        afc[0].q[1] = *(const uint4*)(aqp + 16);

        // o4 + em hoisted: latency hides under the MFMA chain (R8 order)
        const int4 o4 = *(const int4*)(obsT + t * BATCH + b0 + quad * 4);
        float emc[TPW][4];
#pragma unroll
        for (int idx = 0; idx < TPW; ++idx) {
            const int n = (idx < RT) ? (idx * 8 + wv) : (32 + wv);
            const int j = n * 16 + mrow;
            emc[idx][0] = BmT[o4.x * SPAD + j];
            emc[idx][1] = BmT[o4.y * SPAD + j];
            emc[idx][2] = BmT[o4.z * SPAD + j];
            emc[idx][3] = BmT[o4.w * SPAD + j];
        }

        f32x4 acc[TPW];
#pragma unroll
        for (int idx = 0; idx < TPW; ++idx) acc[idx] = (f32x4)0.f;

#pragma unroll
        for (int c = 0; c < NCH; ++c) {
            if (c + 1 < NCH) {                 // prefetch next chunk (global+LDS)
                gs[(c + 1) & 1][0] = sp[((c + 1) * 2 + 0) * 64];
                gs[(c + 1) & 1][1] = sp[((c + 1) * 2 + 1) * 64];
                afc[(c + 1) & 1].q[0] = *(const uint4*)(aqp + (c + 1) * 128);
                afc[(c + 1) & 1].q[1] = *(const uint4*)(aqp + (c + 1) * 128 + 16);
            }
            const i32x8 a = afc[c & 1].v;
#pragma unroll
            for (int rt = 0; rt < RT; ++rt) {
                Frag bf;
                bf.q[0] = areg[rt][c][0];
                bf.q[1] = areg[rt][c][1];
                acc[rt] = MFMA_SCALED(a, bf.v, acc[rt]);
            }
            {
                Frag bf;
                bf.q[0] = gs[c & 1][0];
                bf.q[1] = gs[c & 1][1];
                acc[4] = MFMA_SCALED(a, bf.v, acc[4]);
            }
        }

        // epilogue: cem overwrites emc (register reuse); DPP row16 reduce
        float pz[4];
#pragma unroll
        for (int r = 0; r < 4; ++r) pz[r] = 0.f;
#pragma unroll
        for (int idx = 0; idx < TPW; ++idx)
#pragma unroll
            for (int r = 0; r < 4; ++r) {
                emc[idx][r] = acc[idx][r] * emc[idx][r];
                pz[r] += emc[idx][r];
            }
#pragma unroll
        for (int r = 0; r < 4; ++r) pz[r] = row16_sum(pz[r]);
        if (mrow == 0) {
            f32x4 v; v[0] = pz[0]; v[1] = pz[1]; v[2] = pz[2]; v[3] = pz[3];
            zpart4[wv][quad] = v;              // one b128 write per quad-lead
        }
        __syncthreads();                       // B1: zpart ready; alphaq reads done
        if (tid < MBX) {
            float z = 0.f;
            for (int w = 0; w < NWAVE; ++w) z += ((float*)zpart4[w])[tid];
            ll += (double)logf(z);
            zsc[tid] = 128.f / z;
        }
        __syncthreads();                       // B2: zsc ready; alphaq writable
        {
            float inv[4];
#pragma unroll
            for (int r = 0; r < 4; ++r) inv[r] = zsc[quad * 4 + r];
#pragma unroll
            for (int idx = 0; idx < TPW; ++idx) {
                const int n = (idx < RT) ? (idx * 8 + wv) : (32 + wv);
                const int j = n * 16 + mrow;
#pragma unroll
                for (int r = 0; r < 4; ++r)
                    alphaq[(quad * 4 + r) * AROW + j] = fp8byte(emc[idx][r] * inv[r]);
            }
        }
        __syncthreads();                       // B3: alphaq ready for next step
    }

    // every step's MFMA carried factor 128*s
    const double LOG128 = 4.852030263919617;
    if (tid < MBX) ll_out[b0 + tid] = ll - 2047.0 * (logs[0] + LOG128);
}

__global__ void k_final(const double* __restrict__ ll, const float* __restrict__ regsum,
                        float* __restrict__ out) {
    double s = 0.0;
    for (int b = 0; b < BATCH; ++b) s += ll[b];
    double loglik_mean = s / BATCH;
    double reg_mean = (double)regsum[0] / NREG;
    out[0] = (float)(-loglik_mean - 4.0 * reg_mean);
}

// ---------- launch ----------------------------------------------------------
extern "C" void kernel_launch(void* const* d_in, const int* in_sizes, int n_in,
                              void* d_out, int out_size, void* d_ws, size_t ws_size,
                              hipStream_t stream) {
    const float* inputs = (const float*)d_in[0];
    const float* A      = (const float*)d_in[1];
    const float* Bm     = (const float*)d_in[2];
    const float* Iv     = (const float*)d_in[3];
    const int*   rf     = (const int*)d_in[4];
    const int*   rt     = (const int*)d_in[5];

    char* ws = (char*)d_ws;
    uint4*    A8c  = (uint4*)ws;                         // 40*5*2*64*16 = 409600
    float*    BmT  = (float*)(ws + 409600);              // 322560
    int*      obsT = (int*)(ws + 732160);                // 262144
    double*   ll   = (double*)(ws + 994304);             // 256
    float*    regs = (float*)(ws + 994560);
    unsigned* mx   = (unsigned*)(ws + 994564);
    float*    sbuf = (float*)(ws + 994568);
    double*   logs = (double*)(ws + 994576);             // ..994584

    hipLaunchKernelGGL(k_init,     dim3(1),   dim3(1),   0, stream, mx);
    hipLaunchKernelGGL(k_max,      dim3(256), dim3(256), 0, stream, A, mx);
    hipLaunchKernelGGL(k_scalefin, dim3(1),   dim3(1),   0, stream, mx, sbuf, logs);
    hipLaunchKernelGGL(k_pack8mx,  dim3(NT, NCH), dim3(64), 0, stream, A, sbuf, A8c);
    hipLaunchKernelGGL(k_bmt,      dim3(E),   dim3(SPAD), 0, stream, Bm, BmT);
    hipLaunchKernelGGL(k_obs,      dim3((BATCH * T + 255) / 256), dim3(256), 0, stream, inputs, obsT);
    hipLaunchKernelGGL(k_reg,      dim3(1),   dim3(1024), 0, stream, A, rf, rt, regs);
    hipLaunchKernelGGL(k_forward,  dim3(NBLK), dim3(THREADS), 0, stream,
                       A8c, BmT, obsT, Iv, logs, ll);
    hipLaunchKernelGGL(k_final,    dim3(1),   dim3(1),   0, stream, ll, regs, (float*)d_out);
}

// Round 11
// 3821.904 us; speedup vs baseline: 1.4962x; 1.4962x over previous
//
#include <hip/hip_runtime.h>
#include <math.h>

// Problem constants
#define S      610
#define E      126
#define BATCH  32
#define T      2048
#define NREG   5000

#define SPAD   640            // padded state dim
#define NT     40             // N-tiles of 16 columns
#define NCH    5              // K-chunks of 128 (5*128 = 640)
#define MBX    16             // batches per block == full MFMA M
#define NBLK   2              // blocks (one per 16-batch group)
#define THREADS 512           // 8 waves
#define NWAVE  8
#define TPW    5              // tiles/wave: idx*8+wv (idx0..2 reg, idx3 LDS-pin) + 32+wv stream
#define RT     3              // register tiles — budget-critical: 120 AGPR (R10 lesson: 4 spills)
#define AROW   688            // alphaq row stride bytes

typedef float f32x4 __attribute__((ext_vector_type(4)));
typedef int   i32x8 __attribute__((ext_vector_type(8)));

union Frag { uint4 q[2]; i32x8 v; };

#define MFMA_SCALED(af, bf, acc) \
    __builtin_amdgcn_mfma_scale_f32_16x16x128_f8f6f4((af), (bf), (acc), 0, 0, \
                                                     0, 0x7F7F7F7F, 0, 0x7F7F7F7F)

// lgkm-only barrier: does NOT drain vmcnt -> global prefetches stay in flight.
__device__ __forceinline__ void ldsbar() {
#if __has_builtin(__builtin_amdgcn_s_waitcnt) && __has_builtin(__builtin_amdgcn_s_barrier)
    __builtin_amdgcn_s_waitcnt(0xC07F);   // vmcnt=63(ignore) exp=7(ignore) lgkm=0
    __builtin_amdgcn_s_barrier();
#else
    __syncthreads();
#endif
}

// DPP row-rotate add (rows of 16 lanes) — all lanes end with the row total.
template <int CTRL>
__device__ __forceinline__ float rotf(float v) {
    int r = __builtin_amdgcn_update_dpp(0, __builtin_bit_cast(int, v),
                                        CTRL, 0xF, 0xF, true);
    return __builtin_bit_cast(float, r);
}
__device__ __forceinline__ float row16_sum(float v) {
    v += rotf<0x128>(v);   // row_ror:8
    v += rotf<0x124>(v);   // row_ror:4
    v += rotf<0x122>(v);   // row_ror:2
    v += rotf<0x121>(v);   // row_ror:1
    return v;
}

// ---------- alphaq layout permutation ---------------------------------------
// Row m stored as 640 bytes; byte position p <-> state j:
//   p<512: idx=p&3, q=p>>2, w=q>>4, mr=q&15 -> j=(idx*8+w)*16+mr
//   p>=512: q=p-512 -> j=(32+(q>>4))*16+(q&15)
// Write side (thread wv,quad,mrow): idx0..3 -> one b32 at (wv*16+mrow)*4; idx4 -> b8.
// Read side (lane mrow,quad): 32 contiguous bytes at c*128+quad*32 (2x b128).
__device__ __host__ __forceinline__ int posf(int j) {
    int n = j >> 4, mr = j & 15;
    return (n < 32) ? ((n & 7) * 16 + mr) * 4 + (n >> 3)
                    : 512 + (n - 32) * 16 + mr;
}
__device__ __forceinline__ int inv_pos(int p) {
    if (p < 512) {
        int idx = p & 3, q = p >> 2;
        return (idx * 8 + (q >> 4)) * 16 + (q & 15);
    }
    int q = p - 512;
    return (32 + (q >> 4)) * 16 + (q & 15);
}

// ---------- fp8 e4m3 encode (HW on gfx950, sw fallback) ---------------------
__device__ __forceinline__ unsigned sw_e4m3_enc(float f) {
    if (!(f > 0.f)) return 0u;
    int e; float fr = frexpf(f, &e);
    if (e - 1 < -6) {
        int q = (int)rintf(f * 512.f);
        if (q > 7) q = 7;
        return (unsigned)q;
    }
    int m = (int)rintf(fr * 16.f) - 8;
    int EE = e - 1;
    if (m == 8) { m = 0; EE += 1; }
    if (EE > 8) { EE = 8; m = 7; }
    return (unsigned)(((EE + 7) << 3) | m);
}
__device__ __forceinline__ unsigned pack_quad(float v0, float v1, float v2, float v3) {
#if __has_builtin(__builtin_amdgcn_cvt_pk_fp8_f32)
    int w = 0;
    w = __builtin_amdgcn_cvt_pk_fp8_f32(v0, v1, w, false);
    w = __builtin_amdgcn_cvt_pk_fp8_f32(v2, v3, w, true);
    return (unsigned)w;
#else
    return sw_e4m3_enc(v0) | (sw_e4m3_enc(v1) << 8) |
           (sw_e4m3_enc(v2) << 16) | (sw_e4m3_enc(v3) << 24);
#endif
}
__device__ __forceinline__ unsigned char fp8byte(float v) {
#if __has_builtin(__builtin_amdgcn_cvt_pk_fp8_f32)
    int w = __builtin_amdgcn_cvt_pk_fp8_f32(v, v, 0, false);
    return (unsigned char)(w & 0xFF);
#else
    return (unsigned char)sw_e4m3_enc(v);
#endif
}

// ---------- prep kernels ----------------------------------------------------
__global__ void k_init(unsigned* __restrict__ maxbuf) { maxbuf[0] = 0u; }

__global__ void k_max(const float* __restrict__ A, unsigned* __restrict__ maxbuf) {
    int tid = blockIdx.x * blockDim.x + threadIdx.x;
    float m = 0.f;
    for (int i = tid; i < S * S; i += gridDim.x * blockDim.x) m = fmaxf(m, A[i]);
#pragma unroll
    for (int off = 1; off < 64; off <<= 1) m = fmaxf(m, __shfl_xor(m, off, 64));
    if ((threadIdx.x & 63) == 0) atomicMax(maxbuf, __float_as_uint(m));
}

__global__ void k_scalefin(const unsigned* __restrict__ maxbuf,
                           float* __restrict__ s_out, double* __restrict__ logs_out) {
    float mx = __uint_as_float(maxbuf[0]);
    float s = 224.f / mx;
    s_out[0] = s;
    logs_out[0] = log((double)s);
}

// Pack A*s into fp8, B-fragment order, with the SAME p->k map as alphaq (inv_pos).
__global__ void k_pack8mx(const float* __restrict__ A, const float* __restrict__ s_in,
                          uint4* __restrict__ A8c) {
    int n = blockIdx.x;      // 0..NT-1
    int c = blockIdx.y;      // 0..NCH-1
    int l = threadIdx.x;     // 0..63
    float s = s_in[0];
    int j = n * 16 + (l & 15);
    int pb0 = c * 128 + (l >> 4) * 32;
#pragma unroll
    for (int h = 0; h < 2; ++h) {
        unsigned dw[4];
#pragma unroll
        for (int r = 0; r < 4; ++r) {
            float v[4];
#pragma unroll
            for (int pb = 0; pb < 4; ++pb) {
                int k = inv_pos(pb0 + h * 16 + r * 4 + pb);
                v[pb] = (k < S && j < S) ? A[k * S + j] * s : 0.f;
            }
            dw[r] = pack_quad(v[0], v[1], v[2], v[3]);
        }
        A8c[((n * NCH + c) * 2 + h) * 64 + l] = make_uint4(dw[0], dw[1], dw[2], dw[3]);
    }
}

__global__ void k_bmt(const float* __restrict__ Bm, float* __restrict__ BmT) {
    int j = threadIdx.x;
    int o = blockIdx.x;
    BmT[o * SPAD + j] = (j < S) ? Bm[j * E + o] : 0.f;
}

// One-hot inputs -> observation symbols, TRANSPOSED: obsT[t*BATCH + b].
__global__ void k_obs(const float* __restrict__ in, int* __restrict__ obsT) {
    int i = blockIdx.x * blockDim.x + threadIdx.x;
    if (i >= BATCH * T) return;
    const float2* p = (const float2*)(in + (size_t)i * E);
    int o = 0;
#pragma unroll
    for (int k = 0; k < E / 2; ++k) {
        float2 v = p[k];
        if (v.x > 0.5f) o = 2 * k;
        if (v.y > 0.5f) o = 2 * k + 1;
    }
    int b = i / T, t = i % T;
    obsT[t * BATCH + b] = o;
}

__global__ void k_reg(const float* __restrict__ A, const int* __restrict__ rf,
                      const int* __restrict__ rt, float* __restrict__ out) {
    __shared__ float wpart[16];
    int tid = threadIdx.x;
    float s = 0.f;
    for (int i = tid; i < NREG; i += 1024)
        s += log1pf(-A[rf[i] * S + rt[i]]);
#pragma unroll
    for (int off = 1; off < 64; off <<= 1) s += __shfl_xor(s, off, 64);
    if ((tid & 63) == 0) wpart[tid >> 6] = s;
    __syncthreads();
    if (tid == 0) {
        float t = 0.f;
        for (int w = 0; w < 16; ++w) t += wpart[w];
        out[0] = t;
    }
}

// ---------- forward recursion: R8 skeleton + vectorized writes + raw barriers
__global__ __launch_bounds__(THREADS, 2) void k_forward(
    const uint4* __restrict__ A8c,
    const float* __restrict__ BmT,
    const int*   __restrict__ obsT,   // [T][BATCH]
    const float* __restrict__ Iv,
    const double* __restrict__ logs,
    double* __restrict__ ll_out)
{
    __shared__ __align__(16) uint4 pinAv[8 * NCH * 2 * 64];     // tiles 24..31, 81920 B
    __shared__ __align__(16) unsigned char alphaq[MBX * AROW];  // 11008 B
    __shared__ __align__(16) float zpart[NWAVE][MBX];
    __shared__ __align__(16) float zsc[MBX];

    const int g    = blockIdx.x;
    const int tid  = threadIdx.x;
    const int wv   = tid >> 6;
    const int lane = tid & 63;
    const int mrow = lane & 15;
    const int quad = lane >> 4;
    const int b0   = g * MBX;

    // Pin tiles 24..31 in LDS.
    for (int i = tid; i < 8 * NCH * 2 * 64; i += THREADS)
        pinAv[i] = A8c[24 * NCH * 2 * 64 + i];

    // Register tiles rt*8+wv, rt=0..2 (120 regs — fits the 256 unified budget).
    uint4 areg[RT][NCH][2];
#pragma unroll
    for (int rt = 0; rt < RT; ++rt)
#pragma unroll
        for (int c = 0; c < NCH; ++c)
#pragma unroll
            for (int h = 0; h < 2; ++h)
                areg[rt][c][h] = A8c[(((rt * 8 + wv) * NCH + c) * 2 + h) * 64 + lane];

    // ---- t = 0: alpha0 = I*em0 exact, per-batch z, quantize (perm layout) --
    double ll = 0.0;
    {
        const int j1 = tid + THREADS;
        const bool hasb = (j1 < SPAD);
        float Ia = (tid < S) ? Iv[tid] : 0.f;
        float Ib = (hasb && j1 < S) ? Iv[j1] : 0.f;
        float v0a[MBX], v0b[MBX], p0[MBX];
#pragma unroll
        for (int m = 0; m < MBX; ++m) {
            int o = obsT[b0 + m];
            v0a[m] = Ia * BmT[o * SPAD + tid];
            v0b[m] = hasb ? Ib * BmT[o * SPAD + j1] : 0.f;
            p0[m] = v0a[m] + v0b[m];
        }
#pragma unroll
        for (int off = 1; off < 64; off <<= 1)
#pragma unroll
            for (int m = 0; m < MBX; ++m) p0[m] += __shfl_xor(p0[m], off, 64);
        if (lane == 0) {
#pragma unroll
            for (int m = 0; m < MBX; ++m) zpart[wv][m] = p0[m];
        }
        __syncthreads();
        if (tid < MBX) {
            float z = 0.f;
            for (int w = 0; w < NWAVE; ++w) z += zpart[w][tid];
            ll = (double)logf(z);
            zsc[tid] = 128.f / z;
        }
        __syncthreads();
        const int pa = posf(tid);
        const int pb = hasb ? posf(j1) : 0;
#pragma unroll
        for (int m = 0; m < MBX; ++m) {
            alphaq[m * AROW + pa] = fp8byte(v0a[m] * zsc[m]);
            if (hasb) alphaq[m * AROW + pb] = fp8byte(v0b[m] * zsc[m]);
        }
        __syncthreads();
    }

    const uint4* sp = A8c + (size_t)((32 + wv) * NCH * 2) * 64 + lane;  // stream tile
    const unsigned char* aqp = alphaq + mrow * AROW + quad * 32;

    // Preload obs + em for t=1 (em for this thread's 5 tiles x 4 batches).
    int4 o4 = *(const int4*)(obsT + 1 * BATCH + b0 + quad * 4);
    float em[TPW][4];
#pragma unroll
    for (int idx = 0; idx < TPW; ++idx) {
        const int n = (idx < 4) ? (idx * 8 + wv) : (32 + wv);
        const int j = n * 16 + mrow;
        em[idx][0] = BmT[o4.x * SPAD + j];
        em[idx][1] = BmT[o4.y * SPAD + j];
        em[idx][2] = BmT[o4.z * SPAD + j];
        em[idx][3] = BmT[o4.w * SPAD + j];
    }

    // ---- main recursion -----------------------------------------------------
    for (int t = 1; t < T; ++t) {
        // ===== phase A: MFMA chain (em already resident from last tail) =====
        uint4 gs[2][2];
        gs[0][0] = sp[0];
        gs[0][1] = sp[64];
        Frag afc[2];
        afc[0].q[0] = *(const uint4*)(aqp);
        afc[0].q[1] = *(const uint4*)(aqp + 16);

        f32x4 acc[TPW];
#pragma unroll
        for (int idx = 0; idx < TPW; ++idx) acc[idx] = (f32x4)0.f;

#pragma unroll
        for (int c = 0; c < NCH; ++c) {
            if (c + 1 < NCH) {
                gs[(c + 1) & 1][0] = sp[((c + 1) * 2 + 0) * 64];
                gs[(c + 1) & 1][1] = sp[((c + 1) * 2 + 1) * 64];
                afc[(c + 1) & 1].q[0] = *(const uint4*)(aqp + (c + 1) * 128);
                afc[(c + 1) & 1].q[1] = *(const uint4*)(aqp + (c + 1) * 128 + 16);
            }
            const i32x8 a = afc[c & 1].v;
            Frag pf;                                   // pin-tile fragment (LDS)
            pf.q[0] = pinAv[((wv * NCH + c) * 2 + 0) * 64 + lane];
            pf.q[1] = pinAv[((wv * NCH + c) * 2 + 1) * 64 + lane];
#pragma unroll
            for (int rt = 0; rt < RT; ++rt) {
                Frag bf;
                bf.q[0] = areg[rt][c][0];
                bf.q[1] = areg[rt][c][1];
                acc[rt] = MFMA_SCALED(a, bf.v, acc[rt]);
            }
            acc[3] = MFMA_SCALED(a, pf.v, acc[3]);
            {
                Frag bf;
                bf.q[0] = gs[c & 1][0];
                bf.q[1] = gs[c & 1][1];
                acc[4] = MFMA_SCALED(a, bf.v, acc[4]);
            }
        }

        // obs for t+1: issue now, stays in flight across the raw barriers
        const int tn = (t + 1 < T) ? t + 1 : t;
        const int4 o4n = *(const int4*)(obsT + tn * BATCH + b0 + quad * 4);

        // ===== epilogue: cem (in place), DPP reduce, zpart publish ==========
        float pz[4];
#pragma unroll
        for (int r = 0; r < 4; ++r) pz[r] = 0.f;
#pragma unroll
        for (int idx = 0; idx < TPW; ++idx)
#pragma unroll
            for (int r = 0; r < 4; ++r) {
                em[idx][r] = acc[idx][r] * em[idx][r];   // em now holds cem
                pz[r] += em[idx][r];
            }
#pragma unroll
        for (int r = 0; r < 4; ++r) pz[r] = row16_sum(pz[r]);
        if (mrow == 0) {
            f32x4 v; v[0] = pz[0]; v[1] = pz[1]; v[2] = pz[2]; v[3] = pz[3];
            *(f32x4*)(&zpart[wv][quad * 4]) = v;
        }
        ldsbar();                              // B1: zpart ready; alphaq reads done

        if (tid < MBX) {
            float z = 0.f;
            for (int w = 0; w < NWAVE; ++w) z += zpart[w][tid];
            ll += (double)logf(z);
            zsc[tid] = 128.f / z;
        }
        // prefetch em for t+1 into cem-dead... (em regs rewritten AFTER their cem
        // values are consumed below — so stage into locals first)
        float emn[TPW][4];
#pragma unroll
        for (int idx = 0; idx < TPW; ++idx) {
            const int n = (idx < 4) ? (idx * 8 + wv) : (32 + wv);
            const int j = n * 16 + mrow;
            emn[idx][0] = BmT[o4n.x * SPAD + j];
            emn[idx][1] = BmT[o4n.y * SPAD + j];
            emn[idx][2] = BmT[o4n.z * SPAD + j];
            emn[idx][3] = BmT[o4n.w * SPAD + j];
        }
        ldsbar();                              // B2: zsc ready; alphaq writable

        // ===== quantize + vectorized writes =================================
        {
            f32x4 zv = *(const f32x4*)(zsc + quad * 4);   // one b128 broadcast
            const int wbase = (wv * 16 + mrow) * 4;
#pragma unroll
            for (int r = 0; r < 4; ++r) {
                const float iv = zv[r];
                unsigned dw = pack_quad(em[0][r] * iv, em[1][r] * iv,
                                        em[2][r] * iv, em[3][r] * iv);
                *(unsigned*)(alphaq + (quad * 4 + r) * AROW + wbase) = dw;
                alphaq[(quad * 4 + r) * AROW + 512 + wv * 16 + mrow] =
                    fp8byte(em[4][r] * iv);
            }
        }
        // move prefetched em into place for next iteration
#pragma unroll
        for (int idx = 0; idx < TPW; ++idx)
#pragma unroll
            for (int r = 0; r < 4; ++r) em[idx][r] = emn[idx][r];
        ldsbar();                              // B3: alphaq ready for next step
    }

    const double LOG128 = 4.852030263919617;
    if (tid < MBX) ll_out[b0 + tid] = ll - 2047.0 * (logs[0] + LOG128);
}

__global__ void k_final(const double* __restrict__ ll, const float* __restrict__ regsum,
                        float* __restrict__ out) {
    double s = 0.0;
    for (int b = 0; b < BATCH; ++b) s += ll[b];
    double loglik_mean = s / BATCH;
    double reg_mean = (double)regsum[0] / NREG;
    out[0] = (float)(-loglik_mean - 4.0 * reg_mean);
}

// ---------- launch ----------------------------------------------------------
extern "C" void kernel_launch(void* const* d_in, const int* in_sizes, int n_in,
                              void* d_out, int out_size, void* d_ws, size_t ws_size,
                              hipStream_t stream) {
    const float* inputs = (const float*)d_in[0];
    const float* A      = (const float*)d_in[1];
    const float* Bm     = (const float*)d_in[2];
    const float* Iv     = (const float*)d_in[3];
    const int*   rf     = (const int*)d_in[4];
    const int*   rt     = (const int*)d_in[5];

    char* ws = (char*)d_ws;
    uint4*    A8c  = (uint4*)ws;                         // 409600
    float*    BmT  = (float*)(ws + 409600);              // 322560
    int*      obsT = (int*)(ws + 732160);                // 262144
    double*   ll   = (double*)(ws + 994304);             // 256
    float*    regs = (float*)(ws + 994560);
    unsigned* mx   = (unsigned*)(ws + 994564);
    float*    sbuf = (float*)(ws + 994568);
    double*   logs = (double*)(ws + 994576);             // ..994584

    hipLaunchKernelGGL(k_init,     dim3(1),   dim3(1),   0, stream, mx);
    hipLaunchKernelGGL(k_max,      dim3(256), dim3(256), 0, stream, A, mx);
    hipLaunchKernelGGL(k_scalefin, dim3(1),   dim3(1),   0, stream, mx, sbuf, logs);
    hipLaunchKernelGGL(k_pack8mx,  dim3(NT, NCH), dim3(64), 0, stream, A, sbuf, A8c);
    hipLaunchKernelGGL(k_bmt,      dim3(E),   dim3(SPAD), 0, stream, Bm, BmT);
    hipLaunchKernelGGL(k_obs,      dim3((BATCH * T + 255) / 256), dim3(256), 0, stream, inputs, obsT);
    hipLaunchKernelGGL(k_reg,      dim3(1),   dim3(1024), 0, stream, A, rf, rt, regs);
    hipLaunchKernelGGL(k_forward,  dim3(NBLK), dim3(THREADS), 0, stream,
                       A8c, BmT, obsT, Iv, logs, ll);
    hipLaunchKernelGGL(k_final,    dim3(1),   dim3(1),   0, stream, ll, regs, (float*)d_out);
}